// Round 1
// baseline (1088.014 us; speedup 1.0000x reference)
//
#include <hip/hip_runtime.h>
#include <hip/hip_bf16.h>

#define BATCH 4
#define NPTS  4096
#define NPTS2 4096
#define CIN   128
#define DIM   64
#define KNN   20
#define UPF   2
#define HPOS  64
#define HATT  256
#define MOUT  8192
#define EPSF  1e-5f

// ---------------------------------------------------------------------------
// proj_q: q_t[b][n][o] = bq[o] + sum_c wq[o][c] * x[b][c][n]
// lanes = n (stride-1 LDS reads), weights wave-uniform (scalar-loadable),
// transpose through LDS for coalesced stores.
// ---------------------------------------------------------------------------
__global__ __launch_bounds__(256) void proj_q(const float* __restrict__ x,
    const float* __restrict__ wq, const float* __restrict__ bq,
    float* __restrict__ q_t) {
  __shared__ float X[CIN][64];
  __shared__ float O[64][65];
  const int b  = blockIdx.x >> 6;
  const int n0 = (blockIdx.x & 63) * 64;
  const int t  = threadIdx.x;
  for (int l = t; l < CIN * 64; l += 256) {
    int c = l >> 6, i = l & 63;
    X[c][i] = x[(b * CIN + c) * NPTS + n0 + i];
  }
  __syncthreads();
  const int n_l = t & 63;
  const int w   = __builtin_amdgcn_readfirstlane(t >> 6);  // wave id 0..3
  float acc[16];
#pragma unroll
  for (int i = 0; i < 16; ++i) acc[i] = bq[w * 16 + i];
  for (int c = 0; c < CIN; ++c) {
    float xv = X[c][n_l];
#pragma unroll
    for (int i = 0; i < 16; ++i) acc[i] += wq[(w * 16 + i) * CIN + c] * xv;
  }
#pragma unroll
  for (int i = 0; i < 16; ++i) O[n_l][w * 16 + i] = acc[i];
  __syncthreads();
  for (int l = t; l < 64 * 64; l += 256) {
    int row = l >> 6, co = l & 63;
    q_t[(b * NPTS + n0 + row) * DIM + co] = O[row][co];
  }
}

// ---------------------------------------------------------------------------
// proj_kv: k_t and v_t from key_feat, same structure as proj_q.
// ---------------------------------------------------------------------------
__global__ __launch_bounds__(256) void proj_kv(const float* __restrict__ x,
    const float* __restrict__ wk, const float* __restrict__ bk,
    const float* __restrict__ wv, const float* __restrict__ bv,
    float* __restrict__ k_t, float* __restrict__ v_t) {
  __shared__ float X[CIN][64];
  __shared__ float O[64][65];
  const int b  = blockIdx.x >> 6;
  const int n0 = (blockIdx.x & 63) * 64;
  const int t  = threadIdx.x;
  for (int l = t; l < CIN * 64; l += 256) {
    int c = l >> 6, i = l & 63;
    X[c][i] = x[(b * CIN + c) * NPTS2 + n0 + i];
  }
  __syncthreads();
  const int n_l = t & 63;
  const int w   = __builtin_amdgcn_readfirstlane(t >> 6);
  float acck[16], accv[16];
#pragma unroll
  for (int i = 0; i < 16; ++i) { acck[i] = bk[w * 16 + i]; accv[i] = bv[w * 16 + i]; }
  for (int c = 0; c < CIN; ++c) {
    float xv = X[c][n_l];
#pragma unroll
    for (int i = 0; i < 16; ++i) {
      acck[i] += wk[(w * 16 + i) * CIN + c] * xv;
      accv[i] += wv[(w * 16 + i) * CIN + c] * xv;
    }
  }
#pragma unroll
  for (int i = 0; i < 16; ++i) O[n_l][w * 16 + i] = acck[i];
  __syncthreads();
  for (int l = t; l < 64 * 64; l += 256)
    k_t[(b * NPTS2 + n0 + (l >> 6)) * DIM + (l & 63)] = O[l >> 6][l & 63];
  __syncthreads();
#pragma unroll
  for (int i = 0; i < 16; ++i) O[n_l][w * 16 + i] = accv[i];
  __syncthreads();
  for (int l = t; l < 64 * 64; l += 256)
    v_t[(b * NPTS2 + n0 + (l >> 6)) * DIM + (l & 63)] = O[l >> 6][l & 63];
}

// ---------------------------------------------------------------------------
// knn: one wave (block=64) per query point. Lanes evaluate 64 candidates per
// iteration; running top-20 is a lane-distributed sorted list (lane l holds
// the l-th smallest). Insert via ballot + shfl_up shift. Strict '<' insert
// keeps earlier (lower) index first on ties, matching lax.top_k stability.
// ---------------------------------------------------------------------------
__global__ __launch_bounds__(64) void knn_kernel(const float* __restrict__ pos1,
    const float* __restrict__ pos2, int* __restrict__ idxout) {
  const int b    = blockIdx.x >> 12;
  const int n    = blockIdx.x & (NPTS - 1);
  const int lane = threadIdx.x;
  const float qx = pos1[(b * 3 + 0) * NPTS + n];
  const float qy = pos1[(b * 3 + 1) * NPTS + n];
  const float qz = pos1[(b * 3 + 2) * NPTS + n];
  const float qn = qx * qx + qy * qy + qz * qz;
  const float* p2x = pos2 + (b * 3 + 0) * NPTS2;
  const float* p2y = pos2 + (b * 3 + 1) * NPTS2;
  const float* p2z = pos2 + (b * 3 + 2) * NPTS2;

  float dl = 3.402823466e38f;  // lane-distributed sorted list
  int   il = 0;

  for (int j0 = 0; j0 < NPTS2; j0 += 64) {
    int j = j0 + lane;
    float x = p2x[j], y = p2y[j], z = p2z[j];
    float d = qn + (x * x + y * y + z * z) - 2.0f * (qx * x + qy * y + qz * z);
    float T = __shfl(dl, 19);
    unsigned long long m = __ballot(d < T);
    while (m) {
      int src = __ffsll(m) - 1;
      m &= m - 1;
      float dd = __shfl(d, src);
      int   jj = j0 + src;
      float T2 = __shfl(dl, 19);
      if (dd < T2) {  // wave-uniform
        float pd = __shfl_up(dl, 1);
        int   pi = __shfl_up(il, 1);
        if (dl > dd) {
          if (lane == 0 || pd <= dd) { dl = dd; il = jj; }
          else                       { dl = pd; il = pi; }
        }
      }
    }
  }
  if (lane < KNN) idxout[(b * NPTS + n) * KNN + lane] = il;
}

// ---------------------------------------------------------------------------
// attn_fused: one block (256 thr) per (b, n). Recomputes pos-MLP in-block,
// builds h and vg, attn layer1 (thread = j over HATT), logits with j-split
// across wave-pairs + LDS partial reduce, softmax over K, aggregation.
// ---------------------------------------------------------------------------
__global__ __launch_bounds__(256) void attn_fused(
    const float* __restrict__ q_t, const float* __restrict__ k_t,
    const float* __restrict__ v_t, const int* __restrict__ idx,
    const float* __restrict__ pos1, const float* __restrict__ pos2,
    const float* __restrict__ pw1, const float* __restrict__ pb1,
    const float* __restrict__ pg,  const float* __restrict__ pbt,
    const float* __restrict__ pm,  const float* __restrict__ pv,
    const float* __restrict__ pw2, const float* __restrict__ pb2,
    const float* __restrict__ aw1, const float* __restrict__ ab1,
    const float* __restrict__ ag,  const float* __restrict__ abt2,
    const float* __restrict__ am,  const float* __restrict__ av,
    const float* __restrict__ awt, const float* __restrict__ abt,
    float* __restrict__ agg) {
  const int b = blockIdx.x >> 12;
  const int n = blockIdx.x & (NPTS - 1);
  const int t = threadIdx.x;

  __shared__ int   sIdx[KNN];
  __shared__ float prel[3][KNN];
  __shared__ float h1s[KNN][HPOS];    // pos hidden
  __shared__ float pes[KNN][DIM];     // pe
  __shared__ float hs[KNN][68];       // h = q - kg + pe (padded)
  __shared__ float vgs[KNN][DIM];     // vg = v_g + pe
  __shared__ float ast[HATT][KNN];    // a
  __shared__ float pl[2][128][21];    // logits partials over j-halves

  if (t < KNN) sIdx[t] = idx[(b * NPTS + n) * KNN + t];
  __syncthreads();
  if (t < 3 * KNN) {
    int c = t / KNN, k = t % KNN;
    prel[c][k] = pos1[(b * 3 + c) * NPTS + n] - pos2[(b * 3 + c) * NPTS2 + sIdx[k]];
  }
  __syncthreads();

  // pos layer1 + BN + ReLU
  for (int l = t; l < KNN * HPOS; l += 256) {
    int k = l >> 6, c = l & 63;
    float acc = pb1[c] + pw1[c * 3] * prel[0][k] + pw1[c * 3 + 1] * prel[1][k]
              + pw1[c * 3 + 2] * prel[2][k];
    float inv = pg[c] / sqrtf(pv[c] + EPSF);
    acc = acc * inv + (pbt[c] - pm[c] * inv);
    h1s[k][c] = fmaxf(acc, 0.0f);
  }
  __syncthreads();

  // pos layer2 -> pe
  for (int l = t; l < KNN * DIM; l += 256) {
    int k = l >> 6, o = l & 63;
    float acc = pb2[o];
    for (int c = 0; c < HPOS; c += 4) {
      float4 w  = *(const float4*)&pw2[o * HPOS + c];
      float4 hv = *(const float4*)&h1s[k][c];
      acc += w.x * hv.x + w.y * hv.y + w.z * hv.z + w.w * hv.w;
    }
    pes[k][o] = acc;
  }
  __syncthreads();

  // h = q - kg + pe ; vg = vgather + pe
  for (int l = t; l < KNN * DIM; l += 256) {
    int k = l >> 6, c = l & 63;
    int j = sIdx[k];
    float pe = pes[k][c];
    hs[k][c]  = q_t[(b * NPTS + n) * DIM + c] - k_t[(b * NPTS2 + j) * DIM + c] + pe;
    vgs[k][c] = v_t[(b * NPTS2 + j) * DIM + c] + pe;
  }
  __syncthreads();

  // attn layer1: a[j][k] = relu(bn(ab1 + aw1[j]·h[k]))
  {
    const int j = t;
    float inv   = ag[j] / sqrtf(av[j] + EPSF);
    float shift = abt2[j] - am[j] * inv;
    float acck[KNN];
#pragma unroll
    for (int k = 0; k < KNN; ++k) acck[k] = ab1[j];
    for (int c = 0; c < DIM; c += 4) {
      float4 w = *(const float4*)&aw1[j * DIM + c];
#pragma unroll
      for (int k = 0; k < KNN; ++k) {
        float4 hv = *(const float4*)&hs[k][c];
        acck[k] += w.x * hv.x + w.y * hv.y + w.z * hv.z + w.w * hv.w;
      }
    }
#pragma unroll
    for (int k = 0; k < KNN; ++k) ast[j][k] = fmaxf(acck[k] * inv + shift, 0.0f);
  }
  __syncthreads();

  // logits L[or][k] = sum_j ast[j][k] * awt[j][or]; or = o*2+r
  // waves: (t>>6)&1 = k-split {0..11, 12..19} (16B-aligned), t>>7 = j-half.
  {
    const int orr = (t & 63) * 2;
    const int kh  = (t >> 6) & 1;
    const int jh  = t >> 7;
    const int jbeg = jh * 128, jend = jbeg + 128;
    if (kh == 0) {
      float a0[12], a1[12];
#pragma unroll
      for (int i = 0; i < 12; ++i) { a0[i] = 0.f; a1[i] = 0.f; }
      for (int j = jbeg; j < jend; ++j) {
        float2 wv = *(const float2*)&awt[j * 128 + orr];
        const float* ap = &ast[j][0];
        float4 x0 = *(const float4*)ap;
        float4 x1 = *(const float4*)(ap + 4);
        float4 x2 = *(const float4*)(ap + 8);
        float avv[12] = {x0.x, x0.y, x0.z, x0.w, x1.x, x1.y, x1.z, x1.w,
                         x2.x, x2.y, x2.z, x2.w};
#pragma unroll
        for (int i = 0; i < 12; ++i) { a0[i] += wv.x * avv[i]; a1[i] += wv.y * avv[i]; }
      }
#pragma unroll
      for (int i = 0; i < 12; ++i) {
        pl[jh][orr][i]     = a0[i];
        pl[jh][orr + 1][i] = a1[i];
      }
    } else {
      float a0[8], a1[8];
#pragma unroll
      for (int i = 0; i < 8; ++i) { a0[i] = 0.f; a1[i] = 0.f; }
      for (int j = jbeg; j < jend; ++j) {
        float2 wv = *(const float2*)&awt[j * 128 + orr];
        const float* ap = &ast[j][12];
        float4 x0 = *(const float4*)ap;
        float4 x1 = *(const float4*)(ap + 4);
        float avv[8] = {x0.x, x0.y, x0.z, x0.w, x1.x, x1.y, x1.z, x1.w};
#pragma unroll
        for (int i = 0; i < 8; ++i) { a0[i] += wv.x * avv[i]; a1[i] += wv.y * avv[i]; }
      }
#pragma unroll
      for (int i = 0; i < 8; ++i) {
        pl[jh][orr][12 + i]     = a0[i];
        pl[jh][orr + 1][12 + i] = a1[i];
      }
    }
  }
  __syncthreads();

  // softmax over k + aggregation; lanes: r = t>>6 (2 waves), o = t&63
  if (t < 128) {
    const int r = t >> 6, o = t & 63;
    const int orr = o * 2 + r;
    float L[KNN];
    float mx = -3.402823466e38f;
#pragma unroll
    for (int k = 0; k < KNN; ++k) {
      L[k] = abt[o] + pl[0][orr][k] + pl[1][orr][k];
      mx = fmaxf(mx, L[k]);
    }
    float s = 0.f;
#pragma unroll
    for (int k = 0; k < KNN; ++k) { L[k] = __expf(L[k] - mx); s += L[k]; }
    float rs = 1.0f / s;
    float acc = 0.f;
#pragma unroll
    for (int k = 0; k < KNN; ++k) acc += L[k] * vgs[k][o];
    agg[((b * NPTS + n) * UPF + r) * DIM + o] = acc * rs;
  }
}

// ---------------------------------------------------------------------------
// out_proj: out[b][o][m] = be[o] + sum_c we[o][c]*agg[b][m][c] + query[b][o][m/2]
// ---------------------------------------------------------------------------
__global__ __launch_bounds__(256) void out_proj(const float* __restrict__ agg,
    const float* __restrict__ we, const float* __restrict__ be,
    const float* __restrict__ query, float* __restrict__ out) {
  __shared__ float A[64][65];
  const int b  = blockIdx.x >> 7;
  const int m0 = (blockIdx.x & 127) * 64;
  const int t  = threadIdx.x;
  for (int l = t; l < 64 * 64; l += 256) {
    int row = l >> 6, c = l & 63;
    A[row][c] = agg[(b * MOUT + m0 + row) * DIM + c];
  }
  __syncthreads();
  const int m_l = t & 63;
  const int w   = __builtin_amdgcn_readfirstlane(t >> 6);
  float acc[32];
#pragma unroll
  for (int i = 0; i < 32; ++i) acc[i] = 0.f;
  for (int c = 0; c < DIM; ++c) {
    float a = A[m_l][c];
#pragma unroll
    for (int i = 0; i < 32; ++i) acc[i] += we[(w * 32 + i) * DIM + c] * a;
  }
  const int m = m0 + m_l;
#pragma unroll
  for (int i = 0; i < 32; ++i) {
    int o = w * 32 + i;
    out[(b * CIN + o) * MOUT + m] = acc[i] + be[o] + query[(b * CIN + o) * NPTS + (m >> 1)];
  }
}

// ---------------------------------------------------------------------------
extern "C" void kernel_launch(void* const* d_in, const int* in_sizes, int n_in,
                              void* d_out, int out_size, void* d_ws, size_t ws_size,
                              hipStream_t stream) {
  (void)in_sizes; (void)n_in; (void)out_size; (void)ws_size;
  const float* pos1     = (const float*)d_in[0];
  const float* query    = (const float*)d_in[1];
  const float* pos2     = (const float*)d_in[2];
  const float* key_feat = (const float*)d_in[3];
  const float* wq  = (const float*)d_in[4];
  const float* bq  = (const float*)d_in[5];
  const float* wk  = (const float*)d_in[6];
  const float* bk  = (const float*)d_in[7];
  const float* wv  = (const float*)d_in[8];
  const float* bv  = (const float*)d_in[9];
  const float* pw1 = (const float*)d_in[10];
  const float* pb1 = (const float*)d_in[11];
  const float* pg  = (const float*)d_in[12];
  const float* pbt = (const float*)d_in[13];
  const float* pm  = (const float*)d_in[14];
  const float* pv  = (const float*)d_in[15];
  const float* pw2 = (const float*)d_in[16];
  const float* pb2 = (const float*)d_in[17];
  const float* aw1 = (const float*)d_in[18];
  const float* ab1 = (const float*)d_in[19];
  const float* ag  = (const float*)d_in[20];
  const float* abt2= (const float*)d_in[21];
  const float* am  = (const float*)d_in[22];
  const float* av  = (const float*)d_in[23];
  const float* awt = (const float*)d_in[24];
  const float* abt = (const float*)d_in[25];
  const float* we  = (const float*)d_in[26];
  const float* be  = (const float*)d_in[27];

  float* ws   = (float*)d_ws;
  float* q_t  = ws;                                   // B*N*64
  float* k_t  = q_t + BATCH * NPTS * DIM;             // B*N2*64
  float* v_t  = k_t + BATCH * NPTS2 * DIM;            // B*N2*64
  float* aggb = v_t + BATCH * NPTS2 * DIM;            // B*8192*64
  int*   idxb = (int*)(aggb + BATCH * MOUT * DIM);    // B*N*20

  proj_q <<<BATCH * (NPTS / 64), 256, 0, stream>>>(query, wq, bq, q_t);
  proj_kv<<<BATCH * (NPTS2 / 64), 256, 0, stream>>>(key_feat, wk, bk, wv, bv, k_t, v_t);
  knn_kernel<<<BATCH * NPTS, 64, 0, stream>>>(pos1, pos2, idxb);
  attn_fused<<<BATCH * NPTS, 256, 0, stream>>>(q_t, k_t, v_t, idxb, pos1, pos2,
      pw1, pb1, pg, pbt, pm, pv, pw2, pb2,
      aw1, ab1, ag, abt2, am, av, awt, abt, aggb);
  out_proj<<<BATCH * (MOUT / 64), 256, 0, stream>>>(aggb, we, be, query, (float*)d_out);
}

// Round 2
// 505.907 us; speedup vs baseline: 2.1506x; 2.1506x over previous
//
#include <hip/hip_runtime.h>
#include <hip/hip_bf16.h>

#define BATCH 4
#define NPTS  4096
#define NPTS2 4096
#define CIN   128
#define DIM   64
#define KNN   20
#define UPF   2
#define HPOS  64
#define HATT  256
#define MOUT  8192
#define EPSF  1e-5f

typedef short short8 __attribute__((ext_vector_type(8)));
typedef float f32x4  __attribute__((ext_vector_type(4)));

__device__ inline unsigned short f2bf(float f) {
  unsigned u = __float_as_uint(f);
  u += 0x7fffu + ((u >> 16) & 1u);
  return (unsigned short)(u >> 16);
}
__device__ inline float bf2f(unsigned short s) {
  return __uint_as_float(((unsigned)s) << 16);
}

// ---------------------------------------------------------------------------
// proj_q: q_t[b][n][o] (unchanged from R1)
// ---------------------------------------------------------------------------
__global__ __launch_bounds__(256) void proj_q(const float* __restrict__ x,
    const float* __restrict__ wq, const float* __restrict__ bq,
    float* __restrict__ q_t) {
  __shared__ float X[CIN][64];
  __shared__ float O[64][65];
  const int b  = blockIdx.x >> 6;
  const int n0 = (blockIdx.x & 63) * 64;
  const int t  = threadIdx.x;
  for (int l = t; l < CIN * 64; l += 256) {
    int c = l >> 6, i = l & 63;
    X[c][i] = x[(b * CIN + c) * NPTS + n0 + i];
  }
  __syncthreads();
  const int n_l = t & 63;
  const int w   = __builtin_amdgcn_readfirstlane(t >> 6);
  float acc[16];
#pragma unroll
  for (int i = 0; i < 16; ++i) acc[i] = bq[w * 16 + i];
  for (int c = 0; c < CIN; ++c) {
    float xv = X[c][n_l];
#pragma unroll
    for (int i = 0; i < 16; ++i) acc[i] += wq[(w * 16 + i) * CIN + c] * xv;
  }
#pragma unroll
  for (int i = 0; i < 16; ++i) O[n_l][w * 16 + i] = acc[i];
  __syncthreads();
  for (int l = t; l < 64 * 64; l += 256)
    q_t[(b * NPTS + n0 + (l >> 6)) * DIM + (l & 63)] = O[l >> 6][l & 63];
}

// ---------------------------------------------------------------------------
// proj_kv (unchanged from R1)
// ---------------------------------------------------------------------------
__global__ __launch_bounds__(256) void proj_kv(const float* __restrict__ x,
    const float* __restrict__ wk, const float* __restrict__ bk,
    const float* __restrict__ wv, const float* __restrict__ bv,
    float* __restrict__ k_t, float* __restrict__ v_t) {
  __shared__ float X[CIN][64];
  __shared__ float O[64][65];
  const int b  = blockIdx.x >> 6;
  const int n0 = (blockIdx.x & 63) * 64;
  const int t  = threadIdx.x;
  for (int l = t; l < CIN * 64; l += 256) {
    int c = l >> 6, i = l & 63;
    X[c][i] = x[(b * CIN + c) * NPTS2 + n0 + i];
  }
  __syncthreads();
  const int n_l = t & 63;
  const int w   = __builtin_amdgcn_readfirstlane(t >> 6);
  float acck[16], accv[16];
#pragma unroll
  for (int i = 0; i < 16; ++i) { acck[i] = bk[w * 16 + i]; accv[i] = bv[w * 16 + i]; }
  for (int c = 0; c < CIN; ++c) {
    float xv = X[c][n_l];
#pragma unroll
    for (int i = 0; i < 16; ++i) {
      acck[i] += wk[(w * 16 + i) * CIN + c] * xv;
      accv[i] += wv[(w * 16 + i) * CIN + c] * xv;
    }
  }
#pragma unroll
  for (int i = 0; i < 16; ++i) O[n_l][w * 16 + i] = acck[i];
  __syncthreads();
  for (int l = t; l < 64 * 64; l += 256)
    k_t[(b * NPTS2 + n0 + (l >> 6)) * DIM + (l & 63)] = O[l >> 6][l & 63];
  __syncthreads();
#pragma unroll
  for (int i = 0; i < 16; ++i) O[n_l][w * 16 + i] = accv[i];
  __syncthreads();
  for (int l = t; l < 64 * 64; l += 256)
    v_t[(b * NPTS2 + n0 + (l >> 6)) * DIM + (l & 63)] = O[l >> 6][l & 63];
}

// ---------------------------------------------------------------------------
// knn (unchanged from R1): lane-distributed sorted top-20 per wave
// ---------------------------------------------------------------------------
__global__ __launch_bounds__(64) void knn_kernel(const float* __restrict__ pos1,
    const float* __restrict__ pos2, int* __restrict__ idxout) {
  const int b    = blockIdx.x >> 12;
  const int n    = blockIdx.x & (NPTS - 1);
  const int lane = threadIdx.x;
  const float qx = pos1[(b * 3 + 0) * NPTS + n];
  const float qy = pos1[(b * 3 + 1) * NPTS + n];
  const float qz = pos1[(b * 3 + 2) * NPTS + n];
  const float qn = qx * qx + qy * qy + qz * qz;
  const float* p2x = pos2 + (b * 3 + 0) * NPTS2;
  const float* p2y = pos2 + (b * 3 + 1) * NPTS2;
  const float* p2z = pos2 + (b * 3 + 2) * NPTS2;
  float dl = 3.402823466e38f;
  int   il = 0;
  for (int j0 = 0; j0 < NPTS2; j0 += 64) {
    int j = j0 + lane;
    float x = p2x[j], y = p2y[j], z = p2z[j];
    float d = qn + (x * x + y * y + z * z) - 2.0f * (qx * x + qy * y + qz * z);
    float T = __shfl(dl, 19);
    unsigned long long m = __ballot(d < T);
    while (m) {
      int src = __ffsll(m) - 1;
      m &= m - 1;
      float dd = __shfl(d, src);
      int   jj = j0 + src;
      float T2 = __shfl(dl, 19);
      if (dd < T2) {
        float pd = __shfl_up(dl, 1);
        int   pi = __shfl_up(il, 1);
        if (dl > dd) {
          if (lane == 0 || pd <= dd) { dl = dd; il = jj; }
          else                       { dl = pd; il = pi; }
        }
      }
    }
  }
  if (lane < KNN) idxout[(b * NPTS + n) * KNN + lane] = il;
}

// ---------------------------------------------------------------------------
// pack_weights: bf16 weight packs + folded BN constants.
//   aw1bf [256][64], awtP[orr][j] = awt[j*128+orr] (bf16, 128x256),
//   pw2bf [64][64], invA/shiftA[256] (attn BN), abtX[orr]=abt[orr>>1],
//   pinvA/pshiftA[64] (pos BN).
// ---------------------------------------------------------------------------
__global__ __launch_bounds__(256) void pack_weights(
    const float* __restrict__ aw1, const float* __restrict__ awt,
    const float* __restrict__ pw2,
    const float* __restrict__ ag,  const float* __restrict__ av,
    const float* __restrict__ abt2, const float* __restrict__ am,
    const float* __restrict__ abt,
    const float* __restrict__ pg,  const float* __restrict__ pv,
    const float* __restrict__ pbt, const float* __restrict__ pm,
    short* __restrict__ aw1bf, short* __restrict__ awtP,
    short* __restrict__ pw2bf, float* __restrict__ invA,
    float* __restrict__ shiftA, float* __restrict__ abtX,
    float* __restrict__ pinvA, float* __restrict__ pshiftA) {
  int i = blockIdx.x * 256 + threadIdx.x;
  if (i < 16384) aw1bf[i] = (short)f2bf(aw1[i]);
  if (i < 32768) {
    int orr = i >> 8, j = i & 255;
    awtP[i] = (short)f2bf(awt[j * 128 + orr]);
  }
  if (i < 4096) pw2bf[i] = (short)f2bf(pw2[i]);
  if (i < 256) {
    float inv = ag[i] / sqrtf(av[i] + EPSF);
    invA[i] = inv;
    shiftA[i] = abt2[i] - am[i] * inv;
  }
  if (i < 128) abtX[i] = abt[i >> 1];
  if (i < 64) {
    float inv = pg[i] / sqrtf(pv[i] + EPSF);
    pinvA[i] = inv;
    pshiftA[i] = pbt[i] - pm[i] * inv;
  }
}

// ---------------------------------------------------------------------------
// attn_mfma: block = 2 query points, 64 columns (2 x 32, neighbors padded
// 20->32). Three chained bf16 MFMA GEMMs (pe, a, logits) + softmax + agg.
// MFMA layouts (m89/m120-verified): A[m=lane&15][k=quad*8+i],
// B[k=quad*8+i][n=lane&15], C/D col=lane&15, row=quad*4+reg.
// LDS regions (manually aliased, 64000 B total):
//   [0      ) vgB  64x72 bf16   (phase B -> E)
//   [9216   ) h1B  64x72 bf16   (P1 -> A)   \ aliased by aL 64x260 bf16 (C->D)
//   [18432  ) peL  64x68 f32    (A -> B)    /
//   [42496  ) hB   64x72 bf16   (B -> C)    aliased by lgc 128x40 f32 (D->E)
//   [62976  ) sj[64] int, [63232) prelL[3][64] f32
// ---------------------------------------------------------------------------
#define SM_VGB   0
#define SM_H1B   9216
#define SM_PEL   18432
#define SM_AL    9216
#define SM_HB    42496
#define SM_LGC   42496
#define SM_SJ    62976
#define SM_PREL  63232

__global__ __launch_bounds__(256) void attn_mfma(
    const float* __restrict__ q_t, const float* __restrict__ k_t,
    const float* __restrict__ v_t, const int* __restrict__ idx,
    const float* __restrict__ pos1, const float* __restrict__ pos2,
    const float* __restrict__ pw1, const float* __restrict__ pb1,
    const float* __restrict__ pinvA, const float* __restrict__ pshiftA,
    const short* __restrict__ pw2bf, const float* __restrict__ pb2,
    const short* __restrict__ aw1bf, const float* __restrict__ ab1,
    const float* __restrict__ invA, const float* __restrict__ shiftA,
    const short* __restrict__ awtP, const float* __restrict__ abtX,
    float* __restrict__ agg) {
  __shared__ __align__(16) char smem[64000];
  const int b  = blockIdx.x >> 11;
  const int n0 = (blockIdx.x & 2047) * 2;
  const int t  = threadIdx.x;
  const int lane = t & 63;
  const int w  = t >> 6;        // wave id
  const int r  = lane & 15;     // tile row/col lane index
  const int q4 = lane >> 4;     // quad

  int*   sj    = (int*)(smem + SM_SJ);
  float* prelL = (float*)(smem + SM_PREL);

  // Phase 0a: neighbor index list (pad kk>=20 -> 0, never used downstream)
  if (t < 64) {
    int p = t >> 5, kk = t & 31;
    sj[t] = (kk < KNN) ? idx[(b * NPTS + n0 + p) * KNN + kk] : 0;
  }
  __syncthreads();
  // Phase 0b: relative positions (pad cols -> 0)
  if (t < 192) {
    int c = t >> 6, col = t & 63;
    int p = col >> 5, kk = col & 31;
    float v = 0.f;
    if (kk < KNN)
      v = pos1[(b * 3 + c) * NPTS + n0 + p] - pos2[(b * 3 + c) * NPTS2 + sj[col]];
    prelL[c * 64 + col] = v;
  }
  __syncthreads();

  // Phase 1: pos-MLP hidden (64 ch) -> h1B bf16 [col][hc] (stride 72)
  {
    int col = t & 63, hg = t >> 6;
    float p0 = prelL[col], p1 = prelL[64 + col], p2 = prelL[128 + col];
#pragma unroll
    for (int ii = 0; ii < 16; ii += 2) {
      int hc = hg * 16 + ii;
      float v0 = pb1[hc]     + pw1[hc*3]   * p0 + pw1[hc*3+1] * p1 + pw1[hc*3+2] * p2;
      float v1 = pb1[hc + 1] + pw1[hc*3+3] * p0 + pw1[hc*3+4] * p1 + pw1[hc*3+5] * p2;
      v0 = fmaxf(v0 * pinvA[hc]     + pshiftA[hc],     0.f);
      v1 = fmaxf(v1 * pinvA[hc + 1] + pshiftA[hc + 1], 0.f);
      unsigned u = (unsigned)f2bf(v0) | ((unsigned)f2bf(v1) << 16);
      *(unsigned*)(smem + SM_H1B + (col * 72 + hc) * 2) = u;
    }
  }
  __syncthreads();

  // Phase A: GEMM0 pe = pw2 @ h1 (+pb2) -> peL f32 [col][o] (stride 68)
  {
    short8 a0[2];
#pragma unroll
    for (int ks = 0; ks < 2; ++ks)
      a0[ks] = *(const short8*)&pw2bf[(w * 16 + r) * 64 + ks * 32 + q4 * 8];
    f32x4 acc[4];
#pragma unroll
    for (int nt = 0; nt < 4; ++nt) acc[nt] = (f32x4){0.f, 0.f, 0.f, 0.f};
#pragma unroll
    for (int ks = 0; ks < 2; ++ks)
#pragma unroll
      for (int nt = 0; nt < 4; ++nt) {
        short8 bv = *(short8*)(smem + SM_H1B + ((nt * 16 + r) * 72 + ks * 32 + q4 * 8) * 2);
        acc[nt] = __builtin_amdgcn_mfma_f32_16x16x32_bf16(a0[ks], bv, acc[nt], 0, 0, 0);
      }
    int o0 = w * 16 + q4 * 4;
    f32x4 pbv = *(const f32x4*)&pb2[o0];
#pragma unroll
    for (int nt = 0; nt < 4; ++nt) {
      f32x4 v = acc[nt] + pbv;
      *(f32x4*)(smem + SM_PEL + ((nt * 16 + r) * 68 + o0) * 4) = v;
    }
  }
  __syncthreads();

  // Phase B: gather k/v rows + build h = q-kg+pe, vg = v+pe (bf16 to LDS)
  {
    int col = t & 63, cg = t >> 6;
    int j  = sj[col];
    int nq = n0 + (col >> 5);
    bool valid = (col & 31) < KNN;
    const float* qrow = q_t + ((size_t)(b * NPTS  + nq)) * DIM + cg * 16;
    const float* krow = k_t + ((size_t)(b * NPTS2 + j))  * DIM + cg * 16;
    const float* vrow = v_t + ((size_t)(b * NPTS2 + j))  * DIM + cg * 16;
#pragma unroll
    for (int u = 0; u < 4; ++u) {
      int c0 = cg * 16 + u * 4;
      f32x4 pe = *(f32x4*)(smem + SM_PEL + (col * 68 + c0) * 4);
      f32x4 qv = *(const f32x4*)(qrow + u * 4);
      f32x4 kv = *(const f32x4*)(krow + u * 4);
      f32x4 vv = *(const f32x4*)(vrow + u * 4);
      f32x4 hv = qv - kv + pe;
      f32x4 gv = vv + pe;
      if (!valid) { hv = (f32x4){0.f,0.f,0.f,0.f}; gv = hv; }
      unsigned long long hp =
          (unsigned long long)f2bf(hv[0])        | ((unsigned long long)f2bf(hv[1]) << 16)
        | ((unsigned long long)f2bf(hv[2]) << 32)| ((unsigned long long)f2bf(hv[3]) << 48);
      unsigned long long gp =
          (unsigned long long)f2bf(gv[0])        | ((unsigned long long)f2bf(gv[1]) << 16)
        | ((unsigned long long)f2bf(gv[2]) << 32)| ((unsigned long long)f2bf(gv[3]) << 48);
      *(unsigned long long*)(smem + SM_HB  + (col * 72 + c0) * 2) = hp;
      *(unsigned long long*)(smem + SM_VGB + (col * 72 + c0) * 2) = gp;
    }
  }
  __syncthreads();

  // Phase C: GEMM1 a = relu(bn(aw1 @ h + ab1)) -> aL bf16 [col][j] (stride 260)
  {
    short8 bs[2][4];
#pragma unroll
    for (int ks = 0; ks < 2; ++ks)
#pragma unroll
      for (int nt = 0; nt < 4; ++nt)
        bs[ks][nt] = *(short8*)(smem + SM_HB + ((nt * 16 + r) * 72 + ks * 32 + q4 * 8) * 2);
#pragma unroll
    for (int mm = 0; mm < 4; ++mm) {
      int mt = w * 4 + mm;
      short8 af0 = *(const short8*)&aw1bf[(mt * 16 + r) * 64 + q4 * 8];
      short8 af1 = *(const short8*)&aw1bf[(mt * 16 + r) * 64 + 32 + q4 * 8];
      f32x4 acc[4];
#pragma unroll
      for (int nt = 0; nt < 4; ++nt) acc[nt] = (f32x4){0.f, 0.f, 0.f, 0.f};
#pragma unroll
      for (int nt = 0; nt < 4; ++nt)
        acc[nt] = __builtin_amdgcn_mfma_f32_16x16x32_bf16(af0, bs[0][nt], acc[nt], 0, 0, 0);
#pragma unroll
      for (int nt = 0; nt < 4; ++nt)
        acc[nt] = __builtin_amdgcn_mfma_f32_16x16x32_bf16(af1, bs[1][nt], acc[nt], 0, 0, 0);
      int j0 = mt * 16 + q4 * 4;
      f32x4 b1 = *(const f32x4*)&ab1[j0];
      f32x4 iv = *(const f32x4*)&invA[j0];
      f32x4 sh = *(const f32x4*)&shiftA[j0];
#pragma unroll
      for (int nt = 0; nt < 4; ++nt) {
        int col = nt * 16 + r;
        float v0 = fmaxf((acc[nt][0] + b1[0]) * iv[0] + sh[0], 0.f);
        float v1 = fmaxf((acc[nt][1] + b1[1]) * iv[1] + sh[1], 0.f);
        float v2 = fmaxf((acc[nt][2] + b1[2]) * iv[2] + sh[2], 0.f);
        float v3 = fmaxf((acc[nt][3] + b1[3]) * iv[3] + sh[3], 0.f);
        unsigned long long pk =
            (unsigned long long)f2bf(v0)        | ((unsigned long long)f2bf(v1) << 16)
          | ((unsigned long long)f2bf(v2) << 32)| ((unsigned long long)f2bf(v3) << 48);
        *(unsigned long long*)(smem + SM_AL + (col * 260 + j0) * 2) = pk;
      }
    }
  }
  __syncthreads();

  // Phase D: GEMM2 logits = awt^T @ a (+abt) -> lgc f32 [orr][p*20+kk] (valid k only)
  {
    f32x4 acc[2][4];
#pragma unroll
    for (int h = 0; h < 2; ++h)
#pragma unroll
      for (int nt = 0; nt < 4; ++nt) acc[h][nt] = (f32x4){0.f, 0.f, 0.f, 0.f};
    for (int ks = 0; ks < 8; ++ks) {
      short8 bsv[4];
#pragma unroll
      for (int nt = 0; nt < 4; ++nt)
        bsv[nt] = *(short8*)(smem + SM_AL + ((nt * 16 + r) * 260 + ks * 32 + q4 * 8) * 2);
#pragma unroll
      for (int h = 0; h < 2; ++h) {
        int mt2 = w * 2 + h;
        short8 af = *(const short8*)&awtP[(mt2 * 16 + r) * 256 + ks * 32 + q4 * 8];
#pragma unroll
        for (int nt = 0; nt < 4; ++nt)
          acc[h][nt] = __builtin_amdgcn_mfma_f32_16x16x32_bf16(af, bsv[nt], acc[h][nt], 0, 0, 0);
      }
    }
    float* lgc = (float*)(smem + SM_LGC);
#pragma unroll
    for (int h = 0; h < 2; ++h) {
      int orr0 = (w * 2 + h) * 16 + q4 * 4;
      f32x4 ab = *(const f32x4*)&abtX[orr0];
#pragma unroll
      for (int nt = 0; nt < 4; ++nt) {
        int col = nt * 16 + r;
        int p = col >> 5, kk = col & 31;
        if (kk < KNN) {
#pragma unroll
          for (int reg = 0; reg < 4; ++reg)
            lgc[(orr0 + reg) * 40 + p * 20 + kk] = acc[h][nt][reg] + ab[reg];
        }
      }
    }
  }
  __syncthreads();

  // Phase E: softmax over k=20 + aggregation with vg
  {
    int orr = t & 127, p = t >> 7;
    int o = orr >> 1, rb = orr & 1;
    float L[20];
#pragma unroll
    for (int u = 0; u < 5; ++u) {
      f32x4 lv = *(f32x4*)(smem + SM_LGC + (orr * 40 + p * 20 + u * 4) * 4);
      L[u * 4 + 0] = lv[0]; L[u * 4 + 1] = lv[1];
      L[u * 4 + 2] = lv[2]; L[u * 4 + 3] = lv[3];
    }
    float mx = L[0];
#pragma unroll
    for (int kk = 1; kk < KNN; ++kk) mx = fmaxf(mx, L[kk]);
    float s = 0.f;
#pragma unroll
    for (int kk = 0; kk < KNN; ++kk) { L[kk] = __expf(L[kk] - mx); s += L[kk]; }
    float rs = 1.0f / s;
    float a = 0.f;
#pragma unroll
    for (int kk = 0; kk < KNN; ++kk) {
      unsigned short gv = *(unsigned short*)(smem + SM_VGB + ((p * 32 + kk) * 72 + o) * 2);
      a += L[kk] * bf2f(gv);
    }
    agg[(((size_t)(b * NPTS + n0 + p)) * UPF + rb) * DIM + o] = a * rs;
  }
}

// ---------------------------------------------------------------------------
// out_proj (unchanged from R1)
// ---------------------------------------------------------------------------
__global__ __launch_bounds__(256) void out_proj(const float* __restrict__ agg,
    const float* __restrict__ we, const float* __restrict__ be,
    const float* __restrict__ query, float* __restrict__ out) {
  __shared__ float A[64][65];
  const int b  = blockIdx.x >> 7;
  const int m0 = (blockIdx.x & 127) * 64;
  const int t  = threadIdx.x;
  for (int l = t; l < 64 * 64; l += 256) {
    int row = l >> 6, c = l & 63;
    A[row][c] = agg[(b * MOUT + m0 + row) * DIM + c];
  }
  __syncthreads();
  const int m_l = t & 63;
  const int w   = __builtin_amdgcn_readfirstlane(t >> 6);
  float acc[32];
#pragma unroll
  for (int i = 0; i < 32; ++i) acc[i] = 0.f;
  for (int c = 0; c < DIM; ++c) {
    float a = A[m_l][c];
#pragma unroll
    for (int i = 0; i < 32; ++i) acc[i] += we[(w * 32 + i) * DIM + c] * a;
  }
  const int m = m0 + m_l;
#pragma unroll
  for (int i = 0; i < 32; ++i) {
    int o = w * 32 + i;
    out[(b * CIN + o) * MOUT + m] = acc[i] + be[o] + query[(b * CIN + o) * NPTS + (m >> 1)];
  }
}

// ---------------------------------------------------------------------------
extern "C" void kernel_launch(void* const* d_in, const int* in_sizes, int n_in,
                              void* d_out, int out_size, void* d_ws, size_t ws_size,
                              hipStream_t stream) {
  (void)in_sizes; (void)n_in; (void)out_size; (void)ws_size;
  const float* pos1     = (const float*)d_in[0];
  const float* query    = (const float*)d_in[1];
  const float* pos2     = (const float*)d_in[2];
  const float* key_feat = (const float*)d_in[3];
  const float* wq  = (const float*)d_in[4];
  const float* bq  = (const float*)d_in[5];
  const float* wk  = (const float*)d_in[6];
  const float* bk  = (const float*)d_in[7];
  const float* wv  = (const float*)d_in[8];
  const float* bv  = (const float*)d_in[9];
  const float* pw1 = (const float*)d_in[10];
  const float* pb1 = (const float*)d_in[11];
  const float* pg  = (const float*)d_in[12];
  const float* pbt = (const float*)d_in[13];
  const float* pm  = (const float*)d_in[14];
  const float* pv  = (const float*)d_in[15];
  const float* pw2 = (const float*)d_in[16];
  const float* pb2 = (const float*)d_in[17];
  const float* aw1 = (const float*)d_in[18];
  const float* ab1 = (const float*)d_in[19];
  const float* ag  = (const float*)d_in[20];
  const float* abt2= (const float*)d_in[21];
  const float* am  = (const float*)d_in[22];
  const float* av  = (const float*)d_in[23];
  const float* awt = (const float*)d_in[24];
  const float* abt = (const float*)d_in[25];
  const float* we  = (const float*)d_in[26];
  const float* be  = (const float*)d_in[27];

  float* ws   = (float*)d_ws;
  float* q_t  = ws;                                   // 1,048,576
  float* k_t  = q_t + BATCH * NPTS * DIM;             // 1,048,576
  float* v_t  = k_t + BATCH * NPTS2 * DIM;            // 1,048,576
  float* aggb = v_t + BATCH * NPTS2 * DIM;            // 2,097,152
  int*   idxb = (int*)(aggb + BATCH * MOUT * DIM);    // 327,680
  short* aw1bf = (short*)(idxb + BATCH * NPTS * KNN); // 16384 sh
  short* awtP  = aw1bf + HATT * DIM;                  // 32768 sh
  short* pw2bf = awtP + 128 * HATT;                   // 4096 sh
  float* invA   = (float*)(pw2bf + DIM * HPOS);       // 256
  float* shiftA = invA + HATT;                        // 256
  float* abtX   = shiftA + HATT;                      // 128
  float* pinvA  = abtX + 128;                         // 64
  float* pshiftA= pinvA + HPOS;                       // 64

  pack_weights<<<128, 256, 0, stream>>>(aw1, awt, pw2, ag, av, abt2, am, abt,
      pg, pv, pbt, pm, aw1bf, awtP, pw2bf, invA, shiftA, abtX, pinvA, pshiftA);
  proj_q <<<BATCH * (NPTS / 64), 256, 0, stream>>>(query, wq, bq, q_t);
  proj_kv<<<BATCH * (NPTS2 / 64), 256, 0, stream>>>(key_feat, wk, bk, wv, bv, k_t, v_t);
  knn_kernel<<<BATCH * NPTS, 64, 0, stream>>>(pos1, pos2, idxb);
  attn_mfma<<<BATCH * NPTS / 2, 256, 0, stream>>>(q_t, k_t, v_t, idxb, pos1, pos2,
      pw1, pb1, pinvA, pshiftA, pw2bf, pb2, aw1bf, ab1, invA, shiftA, awtP, abtX, aggb);
  out_proj<<<BATCH * (MOUT / 64), 256, 0, stream>>>(aggb, we, be, query, (float*)d_out);
}

// Round 3
// 461.328 us; speedup vs baseline: 2.3584x; 1.0966x over previous
//
#include <hip/hip_runtime.h>
#include <hip/hip_bf16.h>

#define BATCH 4
#define NPTS  4096
#define NPTS2 4096
#define CIN   128
#define DIM   64
#define KNN   20
#define UPF   2
#define HPOS  64
#define HATT  256
#define MOUT  8192
#define EPSF  1e-5f

typedef _Float16 h16x8 __attribute__((ext_vector_type(8)));
typedef _Float16 h16x4 __attribute__((ext_vector_type(4)));
typedef _Float16 h16x2 __attribute__((ext_vector_type(2)));
typedef float    f32x4 __attribute__((ext_vector_type(4)));

__device__ inline float rdlane(float v, int src) {
  return __int_as_float(__builtin_amdgcn_readlane(__float_as_int(v), src));
}

// ---------------------------------------------------------------------------
// proj_q: q_t[b][n][o] (unchanged)
// ---------------------------------------------------------------------------
__global__ __launch_bounds__(256) void proj_q(const float* __restrict__ x,
    const float* __restrict__ wq, const float* __restrict__ bq,
    float* __restrict__ q_t) {
  __shared__ float X[CIN][64];
  __shared__ float O[64][65];
  const int b  = blockIdx.x >> 6;
  const int n0 = (blockIdx.x & 63) * 64;
  const int t  = threadIdx.x;
  for (int l = t; l < CIN * 64; l += 256) {
    int c = l >> 6, i = l & 63;
    X[c][i] = x[(b * CIN + c) * NPTS + n0 + i];
  }
  __syncthreads();
  const int n_l = t & 63;
  const int w   = __builtin_amdgcn_readfirstlane(t >> 6);
  float acc[16];
#pragma unroll
  for (int i = 0; i < 16; ++i) acc[i] = bq[w * 16 + i];
  for (int c = 0; c < CIN; ++c) {
    float xv = X[c][n_l];
#pragma unroll
    for (int i = 0; i < 16; ++i) acc[i] += wq[(w * 16 + i) * CIN + c] * xv;
  }
#pragma unroll
  for (int i = 0; i < 16; ++i) O[n_l][w * 16 + i] = acc[i];
  __syncthreads();
  for (int l = t; l < 64 * 64; l += 256)
    q_t[(b * NPTS + n0 + (l >> 6)) * DIM + (l & 63)] = O[l >> 6][l & 63];
}

// ---------------------------------------------------------------------------
// proj_kv (unchanged)
// ---------------------------------------------------------------------------
__global__ __launch_bounds__(256) void proj_kv(const float* __restrict__ x,
    const float* __restrict__ wk, const float* __restrict__ bk,
    const float* __restrict__ wv, const float* __restrict__ bv,
    float* __restrict__ k_t, float* __restrict__ v_t) {
  __shared__ float X[CIN][64];
  __shared__ float O[64][65];
  const int b  = blockIdx.x >> 6;
  const int n0 = (blockIdx.x & 63) * 64;
  const int t  = threadIdx.x;
  for (int l = t; l < CIN * 64; l += 256) {
    int c = l >> 6, i = l & 63;
    X[c][i] = x[(b * CIN + c) * NPTS2 + n0 + i];
  }
  __syncthreads();
  const int n_l = t & 63;
  const int w   = __builtin_amdgcn_readfirstlane(t >> 6);
  float acck[16], accv[16];
#pragma unroll
  for (int i = 0; i < 16; ++i) { acck[i] = bk[w * 16 + i]; accv[i] = bv[w * 16 + i]; }
  for (int c = 0; c < CIN; ++c) {
    float xv = X[c][n_l];
#pragma unroll
    for (int i = 0; i < 16; ++i) {
      acck[i] += wk[(w * 16 + i) * CIN + c] * xv;
      accv[i] += wv[(w * 16 + i) * CIN + c] * xv;
    }
  }
#pragma unroll
  for (int i = 0; i < 16; ++i) O[n_l][w * 16 + i] = acck[i];
  __syncthreads();
  for (int l = t; l < 64 * 64; l += 256)
    k_t[(b * NPTS2 + n0 + (l >> 6)) * DIM + (l & 63)] = O[l >> 6][l & 63];
  __syncthreads();
#pragma unroll
  for (int i = 0; i < 16; ++i) O[n_l][w * 16 + i] = accv[i];
  __syncthreads();
  for (int l = t; l < 64 * 64; l += 256)
    v_t[(b * NPTS2 + n0 + (l >> 6)) * DIM + (l & 63)] = O[l >> 6][l & 63];
}

// ---------------------------------------------------------------------------
// knn: lane-distributed sorted top-20 per wave. R3: scalar-indexed shuffles
// (threshold @lane19, candidate broadcast) use v_readlane (VALU) instead of
// ds_bpermute -> only the 2 parallel shfl_up DS ops remain per insert.
// ---------------------------------------------------------------------------
__global__ __launch_bounds__(64) void knn_kernel(const float* __restrict__ pos1,
    const float* __restrict__ pos2, int* __restrict__ idxout) {
  const int b    = blockIdx.x >> 12;
  const int n    = blockIdx.x & (NPTS - 1);
  const int lane = threadIdx.x;
  const float qx = pos1[(b * 3 + 0) * NPTS + n];
  const float qy = pos1[(b * 3 + 1) * NPTS + n];
  const float qz = pos1[(b * 3 + 2) * NPTS + n];
  const float qn = qx * qx + qy * qy + qz * qz;
  const float* p2x = pos2 + (b * 3 + 0) * NPTS2;
  const float* p2y = pos2 + (b * 3 + 1) * NPTS2;
  const float* p2z = pos2 + (b * 3 + 2) * NPTS2;
  float dl = 3.402823466e38f;
  int   il = 0;
  for (int j0 = 0; j0 < NPTS2; j0 += 64) {
    int j = j0 + lane;
    float x = p2x[j], y = p2y[j], z = p2z[j];
    float d = qn + (x * x + y * y + z * z) - 2.0f * (qx * x + qy * y + qz * z);
    float T = rdlane(dl, 19);
    unsigned long long m = __ballot(d < T);
    while (m) {
      int src = __ffsll(m) - 1;
      m &= m - 1;
      float dd = rdlane(d, src);
      if (dd < T) {
        int jj = j0 + src;
        float pd = __shfl_up(dl, 1);
        int   pi = __shfl_up(il, 1);
        if (dl > dd) {
          if (lane == 0 || pd <= dd) { dl = dd; il = jj; }
          else                       { dl = pd; il = pi; }
        }
        T = rdlane(dl, 19);
      }
    }
  }
  if (lane < KNN) idxout[(b * NPTS + n) * KNN + lane] = il;
}

// ---------------------------------------------------------------------------
// pack_weights: fp16 weight packs + folded BN constants.
// ---------------------------------------------------------------------------
__global__ __launch_bounds__(256) void pack_weights(
    const float* __restrict__ aw1, const float* __restrict__ awt,
    const float* __restrict__ pw2,
    const float* __restrict__ ag,  const float* __restrict__ av,
    const float* __restrict__ abt2, const float* __restrict__ am,
    const float* __restrict__ abt,
    const float* __restrict__ pg,  const float* __restrict__ pv,
    const float* __restrict__ pbt, const float* __restrict__ pm,
    _Float16* __restrict__ aw1h, _Float16* __restrict__ awtP,
    _Float16* __restrict__ pw2h, float* __restrict__ invA,
    float* __restrict__ shiftA, float* __restrict__ abtX,
    float* __restrict__ pinvA, float* __restrict__ pshiftA) {
  int i = blockIdx.x * 256 + threadIdx.x;
  if (i < 16384) aw1h[i] = (_Float16)aw1[i];
  if (i < 32768) {
    int orr = i >> 8, j = i & 255;
    awtP[i] = (_Float16)awt[j * 128 + orr];
  }
  if (i < 4096) pw2h[i] = (_Float16)pw2[i];
  if (i < 256) {
    float inv = ag[i] / sqrtf(av[i] + EPSF);
    invA[i] = inv;
    shiftA[i] = abt2[i] - am[i] * inv;
  }
  if (i < 128) abtX[i] = abt[i >> 1];
  if (i < 64) {
    float inv = pg[i] / sqrtf(pv[i] + EPSF);
    pinvA[i] = inv;
    pshiftA[i] = pbt[i] - pm[i] * inv;
  }
}

// ---------------------------------------------------------------------------
// attn_mfma (R3): all on-chip tensors fp16; LDS packed to 53248 B -> 3
// blocks/CU. LDS lifetime map:
//   [0     , 9216 ) h1B 64x72 f16   (P1 -> A)  \
//   [9216  ,26624 ) peL 64x68 f32   (A  -> B)   } overwritten by aL 64x260 f16 (C->D)
//   [26624 ,26880 ) sj  64 int      (P0 -> B)  /
//   [33280 ,42496 ) vgB 64x72 f16   (B -> E)
//   [42496 ,51712 ) hB  64x72 f16   (B -> C);  aliased by lgc 128x42 f16 (D->E)
// ---------------------------------------------------------------------------
#define SM_H1B   0
#define SM_PEL   9216
#define SM_SJ    26624
#define SM_AL    0
#define SM_VGB   33280
#define SM_HB    42496
#define SM_LGC   42496

__global__ __launch_bounds__(256, 3) void attn_mfma(
    const float* __restrict__ q_t, const float* __restrict__ k_t,
    const float* __restrict__ v_t, const int* __restrict__ idx,
    const float* __restrict__ pos1, const float* __restrict__ pos2,
    const float* __restrict__ pw1, const float* __restrict__ pb1,
    const float* __restrict__ pinvA, const float* __restrict__ pshiftA,
    const _Float16* __restrict__ pw2h, const float* __restrict__ pb2,
    const _Float16* __restrict__ aw1h, const float* __restrict__ ab1,
    const float* __restrict__ invA, const float* __restrict__ shiftA,
    const _Float16* __restrict__ awtP, const float* __restrict__ abtX,
    float* __restrict__ agg) {
  __shared__ __align__(16) char smem[53248];
  const int b  = blockIdx.x >> 11;
  const int n0 = (blockIdx.x & 2047) * 2;
  const int t  = threadIdx.x;
  const int lane = t & 63;
  const int w  = t >> 6;        // wave id
  const int r  = lane & 15;     // tile row/col lane index
  const int q4 = lane >> 4;     // quad

  int* sj = (int*)(smem + SM_SJ);

  // Phase 0: neighbor index list (pad kk>=20 -> 0)
  if (t < 64) {
    int p = t >> 5, kk = t & 31;
    sj[t] = (kk < KNN) ? idx[(b * NPTS + n0 + p) * KNN + kk] : 0;
  }
  __syncthreads();

  // Phase 1: pos-MLP hidden (direct pos loads, no prel LDS)
  {
    int col = t & 63, hg = t >> 6;
    int p = col >> 5, kk = col & 31;
    int j = sj[col];
    float p0 = 0.f, p1 = 0.f, p2 = 0.f;
    if (kk < KNN) {
      int nq = n0 + p;
      p0 = pos1[(b * 3 + 0) * NPTS + nq] - pos2[(b * 3 + 0) * NPTS2 + j];
      p1 = pos1[(b * 3 + 1) * NPTS + nq] - pos2[(b * 3 + 1) * NPTS2 + j];
      p2 = pos1[(b * 3 + 2) * NPTS + nq] - pos2[(b * 3 + 2) * NPTS2 + j];
    }
#pragma unroll
    for (int ii = 0; ii < 16; ii += 2) {
      int hc = hg * 16 + ii;
      float v0 = pb1[hc]     + pw1[hc*3]   * p0 + pw1[hc*3+1] * p1 + pw1[hc*3+2] * p2;
      float v1 = pb1[hc + 1] + pw1[hc*3+3] * p0 + pw1[hc*3+4] * p1 + pw1[hc*3+5] * p2;
      v0 = fmaxf(v0 * pinvA[hc]     + pshiftA[hc],     0.f);
      v1 = fmaxf(v1 * pinvA[hc + 1] + pshiftA[hc + 1], 0.f);
      h16x2 pk = {(_Float16)v0, (_Float16)v1};
      *(h16x2*)(smem + SM_H1B + ((col * 72 + hc) * 2)) = pk;
    }
  }
  __syncthreads();

  // Phase A: GEMM0 pe = pw2 @ h1 (+pb2) -> peL f32 [col][o] (stride 68)
  {
    h16x8 a0[2];
#pragma unroll
    for (int ks = 0; ks < 2; ++ks)
      a0[ks] = *(const h16x8*)&pw2h[(w * 16 + r) * 64 + ks * 32 + q4 * 8];
    f32x4 acc[4];
#pragma unroll
    for (int nt = 0; nt < 4; ++nt) acc[nt] = (f32x4){0.f, 0.f, 0.f, 0.f};
#pragma unroll
    for (int ks = 0; ks < 2; ++ks)
#pragma unroll
      for (int nt = 0; nt < 4; ++nt) {
        h16x8 bv = *(h16x8*)(smem + SM_H1B + ((nt * 16 + r) * 72 + ks * 32 + q4 * 8) * 2);
        acc[nt] = __builtin_amdgcn_mfma_f32_16x16x32_f16(a0[ks], bv, acc[nt], 0, 0, 0);
      }
    int o0 = w * 16 + q4 * 4;
    f32x4 pbv = *(const f32x4*)&pb2[o0];
#pragma unroll
    for (int nt = 0; nt < 4; ++nt) {
      f32x4 v = acc[nt] + pbv;
      *(f32x4*)(smem + SM_PEL + ((nt * 16 + r) * 68 + o0) * 4) = v;
    }
  }
  __syncthreads();

  // Phase B: gather k/v rows + build h = q-kg+pe, vg = v+pe (f16 to LDS)
  {
    int col = t & 63, cg = t >> 6;
    int j  = sj[col];
    int nq = n0 + (col >> 5);
    bool valid = (col & 31) < KNN;
    const float* qrow = q_t + ((size_t)(b * NPTS  + nq)) * DIM + cg * 16;
    const float* krow = k_t + ((size_t)(b * NPTS2 + j))  * DIM + cg * 16;
    const float* vrow = v_t + ((size_t)(b * NPTS2 + j))  * DIM + cg * 16;
#pragma unroll
    for (int u = 0; u < 4; ++u) {
      int c0 = cg * 16 + u * 4;
      f32x4 pe = *(f32x4*)(smem + SM_PEL + (col * 68 + c0) * 4);
      f32x4 qv = *(const f32x4*)(qrow + u * 4);
      f32x4 kv = *(const f32x4*)(krow + u * 4);
      f32x4 vv = *(const f32x4*)(vrow + u * 4);
      f32x4 hv = qv - kv + pe;
      f32x4 gv = vv + pe;
      if (!valid) { hv = (f32x4){0.f,0.f,0.f,0.f}; gv = hv; }
      h16x4 hp = {(_Float16)hv[0], (_Float16)hv[1], (_Float16)hv[2], (_Float16)hv[3]};
      h16x4 gp = {(_Float16)gv[0], (_Float16)gv[1], (_Float16)gv[2], (_Float16)gv[3]};
      *(h16x4*)(smem + SM_HB  + (col * 72 + c0) * 2) = hp;
      *(h16x4*)(smem + SM_VGB + (col * 72 + c0) * 2) = gp;
    }
  }
  __syncthreads();

  // Phase C: GEMM1 a = relu(bn(aw1 @ h + ab1)) -> aL f16 [col][j] (stride 260)
  {
    h16x8 bs[2][4];
#pragma unroll
    for (int ks = 0; ks < 2; ++ks)
#pragma unroll
      for (int nt = 0; nt < 4; ++nt)
        bs[ks][nt] = *(h16x8*)(smem + SM_HB + ((nt * 16 + r) * 72 + ks * 32 + q4 * 8) * 2);
#pragma unroll
    for (int mm = 0; mm < 4; ++mm) {
      int mt = w * 4 + mm;
      h16x8 af0 = *(const h16x8*)&aw1h[(mt * 16 + r) * 64 + q4 * 8];
      h16x8 af1 = *(const h16x8*)&aw1h[(mt * 16 + r) * 64 + 32 + q4 * 8];
      f32x4 acc[4];
#pragma unroll
      for (int nt = 0; nt < 4; ++nt) acc[nt] = (f32x4){0.f, 0.f, 0.f, 0.f};
#pragma unroll
      for (int nt = 0; nt < 4; ++nt)
        acc[nt] = __builtin_amdgcn_mfma_f32_16x16x32_f16(af0, bs[0][nt], acc[nt], 0, 0, 0);
#pragma unroll
      for (int nt = 0; nt < 4; ++nt)
        acc[nt] = __builtin_amdgcn_mfma_f32_16x16x32_f16(af1, bs[1][nt], acc[nt], 0, 0, 0);
      int j0 = mt * 16 + q4 * 4;
      f32x4 b1 = *(const f32x4*)&ab1[j0];
      f32x4 iv = *(const f32x4*)&invA[j0];
      f32x4 sh = *(const f32x4*)&shiftA[j0];
#pragma unroll
      for (int nt = 0; nt < 4; ++nt) {
        int col = nt * 16 + r;
        float v0 = fmaxf((acc[nt][0] + b1[0]) * iv[0] + sh[0], 0.f);
        float v1 = fmaxf((acc[nt][1] + b1[1]) * iv[1] + sh[1], 0.f);
        float v2 = fmaxf((acc[nt][2] + b1[2]) * iv[2] + sh[2], 0.f);
        float v3 = fmaxf((acc[nt][3] + b1[3]) * iv[3] + sh[3], 0.f);
        h16x4 pk = {(_Float16)v0, (_Float16)v1, (_Float16)v2, (_Float16)v3};
        *(h16x4*)(smem + SM_AL + (col * 260 + j0) * 2) = pk;
      }
    }
  }
  __syncthreads();

  // Phase D: GEMM2 logits = awt^T @ a (+abt) -> lgc f16 [orr][p*20+kk] (stride 42)
  {
    f32x4 acc[2][4];
#pragma unroll
    for (int h = 0; h < 2; ++h)
#pragma unroll
      for (int nt = 0; nt < 4; ++nt) acc[h][nt] = (f32x4){0.f, 0.f, 0.f, 0.f};
    for (int ks = 0; ks < 8; ++ks) {
      h16x8 bsv[4];
#pragma unroll
      for (int nt = 0; nt < 4; ++nt)
        bsv[nt] = *(h16x8*)(smem + SM_AL + ((nt * 16 + r) * 260 + ks * 32 + q4 * 8) * 2);
#pragma unroll
      for (int h = 0; h < 2; ++h) {
        int mt2 = w * 2 + h;
        h16x8 af = *(const h16x8*)&awtP[(mt2 * 16 + r) * 256 + ks * 32 + q4 * 8];
#pragma unroll
        for (int nt = 0; nt < 4; ++nt)
          acc[h][nt] = __builtin_amdgcn_mfma_f32_16x16x32_f16(af, bsv[nt], acc[h][nt], 0, 0, 0);
      }
    }
#pragma unroll
    for (int h = 0; h < 2; ++h) {
      int orr0 = (w * 2 + h) * 16 + q4 * 4;
      f32x4 ab = *(const f32x4*)&abtX[orr0];
#pragma unroll
      for (int nt = 0; nt < 4; ++nt) {
        int col = nt * 16 + r;
        int p = col >> 5, kk = col & 31;
        if (kk < KNN) {
#pragma unroll
          for (int reg = 0; reg < 4; ++reg)
            *(_Float16*)(smem + SM_LGC + (((orr0 + reg) * 42 + p * 20 + kk) * 2)) =
                (_Float16)(acc[h][nt][reg] + ab[reg]);
        }
      }
    }
  }
  __syncthreads();

  // Phase E: softmax over k=20 + aggregation with vg
  {
    int orr = t & 127, p = t >> 7;
    int o = orr >> 1, rb = orr & 1;
    float L[20];
#pragma unroll
    for (int u = 0; u < 10; ++u) {
      h16x2 lv = *(h16x2*)(smem + SM_LGC + ((orr * 42 + p * 20 + u * 2) * 2));
      L[u * 2]     = (float)lv[0];
      L[u * 2 + 1] = (float)lv[1];
    }
    float mx = L[0];
#pragma unroll
    for (int kk = 1; kk < KNN; ++kk) mx = fmaxf(mx, L[kk]);
    float s = 0.f;
#pragma unroll
    for (int kk = 0; kk < KNN; ++kk) { L[kk] = __expf(L[kk] - mx); s += L[kk]; }
    float rs = 1.0f / s;
    float a = 0.f;
#pragma unroll
    for (int kk = 0; kk < KNN; ++kk) {
      _Float16 gv = *(_Float16*)(smem + SM_VGB + ((p * 32 + kk) * 72 + o) * 2);
      a += L[kk] * (float)gv;
    }
    agg[(((size_t)(b * NPTS + n0 + p)) * UPF + rb) * DIM + o] = a * rs;
  }
}

// ---------------------------------------------------------------------------
// out_proj (unchanged)
// ---------------------------------------------------------------------------
__global__ __launch_bounds__(256) void out_proj(const float* __restrict__ agg,
    const float* __restrict__ we, const float* __restrict__ be,
    const float* __restrict__ query, float* __restrict__ out) {
  __shared__ float A[64][65];
  const int b  = blockIdx.x >> 7;
  const int m0 = (blockIdx.x & 127) * 64;
  const int t  = threadIdx.x;
  for (int l = t; l < 64 * 64; l += 256) {
    int row = l >> 6, c = l & 63;
    A[row][c] = agg[(b * MOUT + m0 + row) * DIM + c];
  }
  __syncthreads();
  const int m_l = t & 63;
  const int w   = __builtin_amdgcn_readfirstlane(t >> 6);
  float acc[32];
#pragma unroll
  for (int i = 0; i < 32; ++i) acc[i] = 0.f;
  for (int c = 0; c < DIM; ++c) {
    float a = A[m_l][c];
#pragma unroll
    for (int i = 0; i < 32; ++i) acc[i] += we[(w * 32 + i) * DIM + c] * a;
  }
  const int m = m0 + m_l;
#pragma unroll
  for (int i = 0; i < 32; ++i) {
    int o = w * 32 + i;
    out[(b * CIN + o) * MOUT + m] = acc[i] + be[o] + query[(b * CIN + o) * NPTS + (m >> 1)];
  }
}

// ---------------------------------------------------------------------------
extern "C" void kernel_launch(void* const* d_in, const int* in_sizes, int n_in,
                              void* d_out, int out_size, void* d_ws, size_t ws_size,
                              hipStream_t stream) {
  (void)in_sizes; (void)n_in; (void)out_size; (void)ws_size;
  const float* pos1     = (const float*)d_in[0];
  const float* query    = (const float*)d_in[1];
  const float* pos2     = (const float*)d_in[2];
  const float* key_feat = (const float*)d_in[3];
  const float* wq  = (const float*)d_in[4];
  const float* bq  = (const float*)d_in[5];
  const float* wk  = (const float*)d_in[6];
  const float* bk  = (const float*)d_in[7];
  const float* wv  = (const float*)d_in[8];
  const float* bv  = (const float*)d_in[9];
  const float* pw1 = (const float*)d_in[10];
  const float* pb1 = (const float*)d_in[11];
  const float* pg  = (const float*)d_in[12];
  const float* pbt = (const float*)d_in[13];
  const float* pm  = (const float*)d_in[14];
  const float* pv  = (const float*)d_in[15];
  const float* pw2 = (const float*)d_in[16];
  const float* pb2 = (const float*)d_in[17];
  const float* aw1 = (const float*)d_in[18];
  const float* ab1 = (const float*)d_in[19];
  const float* ag  = (const float*)d_in[20];
  const float* abt2= (const float*)d_in[21];
  const float* am  = (const float*)d_in[22];
  const float* av  = (const float*)d_in[23];
  const float* awt = (const float*)d_in[24];
  const float* abt = (const float*)d_in[25];
  const float* we  = (const float*)d_in[26];
  const float* be  = (const float*)d_in[27];

  float* ws   = (float*)d_ws;
  float* q_t  = ws;                                   // B*N*64
  float* k_t  = q_t + BATCH * NPTS * DIM;
  float* v_t  = k_t + BATCH * NPTS2 * DIM;
  float* aggb = v_t + BATCH * NPTS2 * DIM;            // B*8192*64
  int*   idxb = (int*)(aggb + BATCH * MOUT * DIM);    // B*N*20
  _Float16* aw1h = (_Float16*)(idxb + BATCH * NPTS * KNN);
  _Float16* awtP = aw1h + HATT * DIM;
  _Float16* pw2h = awtP + 128 * HATT;
  float* invA    = (float*)(pw2h + DIM * HPOS);
  float* shiftA  = invA + HATT;
  float* abtX    = shiftA + HATT;
  float* pinvA   = abtX + 128;
  float* pshiftA = pinvA + HPOS;

  pack_weights<<<128, 256, 0, stream>>>(aw1, awt, pw2, ag, av, abt2, am, abt,
      pg, pv, pbt, pm, aw1h, awtP, pw2h, invA, shiftA, abtX, pinvA, pshiftA);
  proj_q <<<BATCH * (NPTS / 64), 256, 0, stream>>>(query, wq, bq, q_t);
  proj_kv<<<BATCH * (NPTS2 / 64), 256, 0, stream>>>(key_feat, wk, bk, wv, bv, k_t, v_t);
  knn_kernel<<<BATCH * NPTS, 64, 0, stream>>>(pos1, pos2, idxb);
  attn_mfma<<<BATCH * NPTS / 2, 256, 0, stream>>>(q_t, k_t, v_t, idxb, pos1, pos2,
      pw1, pb1, pinvA, pshiftA, pw2h, pb2, aw1h, ab1, invA, shiftA, awtP, abtX, aggb);
  out_proj<<<BATCH * (MOUT / 64), 256, 0, stream>>>(aggb, we, be, query, (float*)d_out);
}

// Round 5
// 401.903 us; speedup vs baseline: 2.7072x; 1.1479x over previous
//
#include <hip/hip_runtime.h>
#include <hip/hip_bf16.h>

#define BATCH 4
#define NPTS  4096
#define NPTS2 4096
#define CIN   128
#define DIM   64
#define KNN   20
#define UPF   2
#define HPOS  64
#define HATT  256
#define MOUT  8192
#define EPSF  1e-5f
#define QPB   3            // queries per attn block
#define BPB   1366         // ceil(4096/3) attn blocks per batch

typedef _Float16 h16x8 __attribute__((ext_vector_type(8)));
typedef _Float16 h16x4 __attribute__((ext_vector_type(4)));
typedef _Float16 h16x2 __attribute__((ext_vector_type(2)));
typedef float    f32x4 __attribute__((ext_vector_type(4)));

__device__ inline float rdlane(float v, int src) {
  return __int_as_float(__builtin_amdgcn_readlane(__float_as_int(v), src));
}

// Bit-exact distance: explicit fma DAG -> identical value in every use site,
// regardless of compiler contraction/scheduling. m2* = -2*q*.
__device__ __forceinline__ float distf(float qn, float m2x, float m2y, float m2z,
                                       float x, float y, float z) {
  float s = __fmaf_rn(x, x, qn);
  s = __fmaf_rn(y, y, s);
  s = __fmaf_rn(z, z, s);
  s = __fmaf_rn(m2x, x, s);
  s = __fmaf_rn(m2y, y, s);
  s = __fmaf_rn(m2z, z, s);
  return s;
}

// ---------------------------------------------------------------------------
// proj_q (unchanged)
// ---------------------------------------------------------------------------
__global__ __launch_bounds__(256) void proj_q(const float* __restrict__ x,
    const float* __restrict__ wq, const float* __restrict__ bq,
    float* __restrict__ q_t) {
  __shared__ float X[CIN][64];
  __shared__ float O[64][65];
  const int b  = blockIdx.x >> 6;
  const int n0 = (blockIdx.x & 63) * 64;
  const int t  = threadIdx.x;
  for (int l = t; l < CIN * 64; l += 256) {
    int c = l >> 6, i = l & 63;
    X[c][i] = x[(b * CIN + c) * NPTS + n0 + i];
  }
  __syncthreads();
  const int n_l = t & 63;
  const int w   = __builtin_amdgcn_readfirstlane(t >> 6);
  float acc[16];
#pragma unroll
  for (int i = 0; i < 16; ++i) acc[i] = bq[w * 16 + i];
  for (int c = 0; c < CIN; ++c) {
    float xv = X[c][n_l];
#pragma unroll
    for (int i = 0; i < 16; ++i) acc[i] += wq[(w * 16 + i) * CIN + c] * xv;
  }
#pragma unroll
  for (int i = 0; i < 16; ++i) O[n_l][w * 16 + i] = acc[i];
  __syncthreads();
  for (int l = t; l < 64 * 64; l += 256)
    q_t[(b * NPTS + n0 + (l >> 6)) * DIM + (l & 63)] = O[l >> 6][l & 63];
}

// ---------------------------------------------------------------------------
// proj_kv (unchanged)
// ---------------------------------------------------------------------------
__global__ __launch_bounds__(256) void proj_kv(const float* __restrict__ x,
    const float* __restrict__ wk, const float* __restrict__ bk,
    const float* __restrict__ wv, const float* __restrict__ bv,
    float* __restrict__ k_t, float* __restrict__ v_t) {
  __shared__ float X[CIN][64];
  __shared__ float O[64][65];
  const int b  = blockIdx.x >> 6;
  const int n0 = (blockIdx.x & 63) * 64;
  const int t  = threadIdx.x;
  for (int l = t; l < CIN * 64; l += 256) {
    int c = l >> 6, i = l & 63;
    X[c][i] = x[(b * CIN + c) * NPTS2 + n0 + i];
  }
  __syncthreads();
  const int n_l = t & 63;
  const int w   = __builtin_amdgcn_readfirstlane(t >> 6);
  float acck[16], accv[16];
#pragma unroll
  for (int i = 0; i < 16; ++i) { acck[i] = bk[w * 16 + i]; accv[i] = bv[w * 16 + i]; }
  for (int c = 0; c < CIN; ++c) {
    float xv = X[c][n_l];
#pragma unroll
    for (int i = 0; i < 16; ++i) {
      acck[i] += wk[(w * 16 + i) * CIN + c] * xv;
      accv[i] += wv[(w * 16 + i) * CIN + c] * xv;
    }
  }
#pragma unroll
  for (int i = 0; i < 16; ++i) O[n_l][w * 16 + i] = acck[i];
  __syncthreads();
  for (int l = t; l < 64 * 64; l += 256)
    k_t[(b * NPTS2 + n0 + (l >> 6)) * DIM + (l & 63)] = O[l >> 6][l & 63];
  __syncthreads();
#pragma unroll
  for (int i = 0; i < 16; ++i) O[n_l][w * 16 + i] = accv[i];
  __syncthreads();
  for (int l = t; l < 64 * 64; l += 256)
    v_t[(b * NPTS2 + n0 + (l >> 6)) * DIM + (l & 63)] = O[l >> 6][l & 63];
}

// ---------------------------------------------------------------------------
// knn v3: two-pass threshold with bit-exact distances (distf).
// Pass 1: per-lane min over its 64 candidates; bitonic-sort minima; T0 =
// 20th smallest (subset k-th order stat >= set k-th: T0 >= true d20).
// Pass 2: ballot(d <= T0*(1+eps)); stable insert into lane-distributed list.
// Fallback (wave-uniform, ~never): full insert pass if <20 collected.
// ---------------------------------------------------------------------------
__global__ __launch_bounds__(256) void knn_kernel(const float* __restrict__ pos1,
    const float* __restrict__ pos2, int* __restrict__ idxout) {
  const int lane = threadIdx.x & 63;
  const int g    = blockIdx.x * 4 + (threadIdx.x >> 6);
  const int b    = g >> 12;
  const int n    = g & (NPTS - 1);
  const float qx = pos1[(b * 3 + 0) * NPTS + n];
  const float qy = pos1[(b * 3 + 1) * NPTS + n];
  const float qz = pos1[(b * 3 + 2) * NPTS + n];
  const float qn = qx * qx + qy * qy + qz * qz;
  const float m2x = -2.0f * qx, m2y = -2.0f * qy, m2z = -2.0f * qz;
  const float* p2x = pos2 + (b * 3 + 0) * NPTS2;
  const float* p2y = pos2 + (b * 3 + 1) * NPTS2;
  const float* p2z = pos2 + (b * 3 + 2) * NPTS2;

  // pass 1: per-lane min
  float mymin = 3.402823466e38f;
  for (int j0 = 0; j0 < NPTS2; j0 += 64) {
    int j = j0 + lane;
    float d = distf(qn, m2x, m2y, m2z, p2x[j], p2y[j], p2z[j]);
    mymin = fminf(mymin, d);
  }
  // bitonic sort (ascending) of the 64 lane-minima
  float v = mymin;
#pragma unroll
  for (int k = 2; k <= 64; k <<= 1) {
#pragma unroll
    for (int jj = k >> 1; jj >= 1; jj >>= 1) {
      float o = __shfl_xor(v, jj);
      bool up = ((lane & k) == 0);
      bool keepmin = (((lane & jj) == 0) == up);
      v = keepmin ? fminf(v, o) : fmaxf(v, o);
    }
  }
  float T0 = rdlane(v, 19);
  T0 = T0 + fmaxf(fabsf(T0) * 4e-6f, 4e-6f);   // safety margin

  // pass 2: collect d <= T0, stable insert
  float dl = 3.402823466e38f;
  int   il = 0;
  for (int j0 = 0; j0 < NPTS2; j0 += 64) {
    int j = j0 + lane;
    float d = distf(qn, m2x, m2y, m2z, p2x[j], p2y[j], p2z[j]);
    unsigned long long m = __ballot(d <= T0);
    while (m) {
      int src = __ffsll(m) - 1;
      m &= m - 1;
      float dd = rdlane(d, src);
      float T  = rdlane(dl, 19);
      if (dd < T) {
        int jj2 = j0 + src;
        float pd = __shfl_up(dl, 1);
        int   pi = __shfl_up(il, 1);
        if (dl > dd) {
          if (lane == 0 || pd <= dd) { dl = dd; il = jj2; }
          else                       { dl = pd; il = pi; }
        }
      }
    }
  }
  // fallback: if fewer than 20 collected (should be impossible), full pass
  if (rdlane(dl, 19) == 3.402823466e38f) {
    dl = 3.402823466e38f; il = 0;
    for (int j0 = 0; j0 < NPTS2; j0 += 64) {
      int j = j0 + lane;
      float d = distf(qn, m2x, m2y, m2z, p2x[j], p2y[j], p2z[j]);
      float T = rdlane(dl, 19);
      unsigned long long m = __ballot(d < T);
      while (m) {
        int src = __ffsll(m) - 1;
        m &= m - 1;
        float dd = rdlane(d, src);
        float T2 = rdlane(dl, 19);
        if (dd < T2) {
          int jj2 = j0 + src;
          float pd = __shfl_up(dl, 1);
          int   pi = __shfl_up(il, 1);
          if (dl > dd) {
            if (lane == 0 || pd <= dd) { dl = dd; il = jj2; }
            else                       { dl = pd; il = pi; }
          }
        }
      }
    }
  }
  if (lane < KNN) idxout[(b * NPTS + n) * KNN + lane] = il;
}

// ---------------------------------------------------------------------------
// pack_weights (unchanged)
// ---------------------------------------------------------------------------
__global__ __launch_bounds__(256) void pack_weights(
    const float* __restrict__ aw1, const float* __restrict__ awt,
    const float* __restrict__ pw2,
    const float* __restrict__ ag,  const float* __restrict__ av,
    const float* __restrict__ abt2, const float* __restrict__ am,
    const float* __restrict__ abt,
    const float* __restrict__ pg,  const float* __restrict__ pv,
    const float* __restrict__ pbt, const float* __restrict__ pm,
    _Float16* __restrict__ aw1h, _Float16* __restrict__ awtP,
    _Float16* __restrict__ pw2h, float* __restrict__ invA,
    float* __restrict__ shiftA, float* __restrict__ abtX,
    float* __restrict__ pinvA, float* __restrict__ pshiftA) {
  int i = blockIdx.x * 256 + threadIdx.x;
  if (i < 16384) aw1h[i] = (_Float16)aw1[i];
  if (i < 32768) {
    int orr = i >> 8, j = i & 255;
    awtP[i] = (_Float16)awt[j * 128 + orr];
  }
  if (i < 4096) pw2h[i] = (_Float16)pw2[i];
  if (i < 256) {
    float inv = ag[i] / sqrtf(av[i] + EPSF);
    invA[i] = inv;
    shiftA[i] = abt2[i] - am[i] * inv;
  }
  if (i < 128) abtX[i] = abt[i >> 1];
  if (i < 64) {
    float inv = pg[i] / sqrtf(pv[i] + EPSF);
    pinvA[i] = inv;
    pshiftA[i] = pbt[i] - pm[i] * inv;
  }
}

// ---------------------------------------------------------------------------
// attn_mfma (R5): 3 queries/block; peL back to f32 (R3 numerics).
// LDS map (51712 B -> 3 blocks/CU):
//   [0    ,33280) aL 64x260 f16 (C->D); before C: h1B@0 (64x72 f16, 9216),
//                 peL@9216 (64x68 f32, 17408), sj@26624 (64 int)
//   [33280,42496) vgB 64x72 f16 (B->E)
//   [42496,51712) hB 64x72 f16 (B->C); lgc aliases @42496 (60x68 f16)
// ---------------------------------------------------------------------------
#define SM_AL    0
#define SM_H1B   0
#define SM_PEL   9216
#define SM_SJ    26624
#define SM_VGB   33280
#define SM_HB    42496
#define SM_LGC   42496

__global__ __launch_bounds__(256, 3) void attn_mfma(
    const float* __restrict__ q_t, const float* __restrict__ k_t,
    const float* __restrict__ v_t, const int* __restrict__ idx,
    const float* __restrict__ pos1, const float* __restrict__ pos2,
    const float* __restrict__ pw1, const float* __restrict__ pb1,
    const float* __restrict__ pinvA, const float* __restrict__ pshiftA,
    const _Float16* __restrict__ pw2h, const float* __restrict__ pb2,
    const _Float16* __restrict__ aw1h, const float* __restrict__ ab1,
    const float* __restrict__ invA, const float* __restrict__ shiftA,
    const _Float16* __restrict__ awtP, const float* __restrict__ abtX,
    float* __restrict__ agg) {
  __shared__ __align__(16) char smem[51712];
  const int b  = blockIdx.x / BPB;
  const int n0 = (blockIdx.x - b * BPB) * QPB;
  const int t  = threadIdx.x;
  const int lane = t & 63;
  const int w  = t >> 6;        // wave id
  const int r  = lane & 15;     // tile lane index
  const int q4 = lane >> 4;     // quad

  int* sj = (int*)(smem + SM_SJ);

  // Phase 0: neighbor indices (invalid cols -> 0)
  if (t < 64) {
    int col = t;
    int p = col / 20, kk = col - p * 20;
    int nq = n0 + p;
    int vI = 0;
    if (p < QPB && nq < NPTS) vI = idx[(b * NPTS + nq) * KNN + kk];
    sj[col] = vI;
  }
  __syncthreads();

  // Prefetch q/k/v gather rows into registers (hide global latency)
  const int colB = t & 63, cgB = t >> 6;
  const int pB = colB / 20;
  const bool okB = (pB < QPB) && (n0 + pB < NPTS);
  f32x4 qv4[4], kv4[4], vv4[4];
  {
    int jB  = sj[colB];
    int nqB = okB ? (n0 + pB) : 0;
    const float* qrow = q_t + ((size_t)(b * NPTS  + nqB)) * DIM + cgB * 16;
    const float* krow = k_t + ((size_t)(b * NPTS2 + jB))  * DIM + cgB * 16;
    const float* vrow = v_t + ((size_t)(b * NPTS2 + jB))  * DIM + cgB * 16;
#pragma unroll
    for (int u = 0; u < 4; ++u) {
      qv4[u] = *(const f32x4*)(qrow + u * 4);
      kv4[u] = *(const f32x4*)(krow + u * 4);
      vv4[u] = *(const f32x4*)(vrow + u * 4);
    }
  }

  // Phase 1: pos-MLP hidden -> h1B f16 [col][hc] stride 72
  {
    int col = t & 63, hg = t >> 6;
    int p = col / 20;
    int j = sj[col];
    bool okc = (p < QPB) && (n0 + p < NPTS);
    float p0 = 0.f, p1 = 0.f, p2 = 0.f;
    if (okc) {
      int nq = n0 + p;
      p0 = pos1[(b * 3 + 0) * NPTS + nq] - pos2[(b * 3 + 0) * NPTS2 + j];
      p1 = pos1[(b * 3 + 1) * NPTS + nq] - pos2[(b * 3 + 1) * NPTS2 + j];
      p2 = pos1[(b * 3 + 2) * NPTS + nq] - pos2[(b * 3 + 2) * NPTS2 + j];
    }
#pragma unroll
    for (int ii = 0; ii < 16; ii += 2) {
      int hc = hg * 16 + ii;
      float v0 = pb1[hc]     + pw1[hc*3]   * p0 + pw1[hc*3+1] * p1 + pw1[hc*3+2] * p2;
      float v1 = pb1[hc + 1] + pw1[hc*3+3] * p0 + pw1[hc*3+4] * p1 + pw1[hc*3+5] * p2;
      v0 = fmaxf(v0 * pinvA[hc]     + pshiftA[hc],     0.f);
      v1 = fmaxf(v1 * pinvA[hc + 1] + pshiftA[hc + 1], 0.f);
      if (!okc) { v0 = 0.f; v1 = 0.f; }
      h16x2 pk = {(_Float16)v0, (_Float16)v1};
      *(h16x2*)(smem + SM_H1B + ((col * 72 + hc) * 2)) = pk;
    }
  }
  __syncthreads();

  // Phase A: GEMM0 pe = pw2 @ h1 (+pb2) -> peL f32 [col][o] stride 68
  {
    h16x8 a0[2];
#pragma unroll
    for (int ks = 0; ks < 2; ++ks)
      a0[ks] = *(const h16x8*)&pw2h[(w * 16 + r) * 64 + ks * 32 + q4 * 8];
    f32x4 acc[4];
#pragma unroll
    for (int nt = 0; nt < 4; ++nt) acc[nt] = (f32x4){0.f, 0.f, 0.f, 0.f};
#pragma unroll
    for (int ks = 0; ks < 2; ++ks)
#pragma unroll
      for (int nt = 0; nt < 4; ++nt) {
        h16x8 bv = *(h16x8*)(smem + SM_H1B + ((nt * 16 + r) * 72 + ks * 32 + q4 * 8) * 2);
        acc[nt] = __builtin_amdgcn_mfma_f32_16x16x32_f16(a0[ks], bv, acc[nt], 0, 0, 0);
      }
    int o0 = w * 16 + q4 * 4;
    f32x4 pbv = *(const f32x4*)&pb2[o0];
#pragma unroll
    for (int nt = 0; nt < 4; ++nt) {
      f32x4 vv = acc[nt] + pbv;
      *(f32x4*)(smem + SM_PEL + ((nt * 16 + r) * 68 + o0) * 4) = vv;
    }
  }
  __syncthreads();

  // Phase B: combine prefetched q/k/v with pe -> hB, vgB (f16)
  {
#pragma unroll
    for (int u = 0; u < 4; ++u) {
      int c0 = cgB * 16 + u * 4;
      f32x4 pe = *(f32x4*)(smem + SM_PEL + (colB * 68 + c0) * 4);
      f32x4 hv = qv4[u] - kv4[u] + pe;
      f32x4 gv = vv4[u] + pe;
      if (!okB) { hv = (f32x4){0.f,0.f,0.f,0.f}; gv = hv; }
      h16x4 hp = {(_Float16)hv[0], (_Float16)hv[1], (_Float16)hv[2], (_Float16)hv[3]};
      h16x4 gp = {(_Float16)gv[0], (_Float16)gv[1], (_Float16)gv[2], (_Float16)gv[3]};
      *(h16x4*)(smem + SM_HB  + (colB * 72 + c0) * 2) = hp;
      *(h16x4*)(smem + SM_VGB + (colB * 72 + c0) * 2) = gp;
    }
  }
  __syncthreads();

  // Phase C: GEMM1 a = relu(bn(aw1 @ h + ab1)) -> aL f16 [col][j] stride 260
  {
    h16x8 bs[2][4];
#pragma unroll
    for (int ks = 0; ks < 2; ++ks)
#pragma unroll
      for (int nt = 0; nt < 4; ++nt)
        bs[ks][nt] = *(h16x8*)(smem + SM_HB + ((nt * 16 + r) * 72 + ks * 32 + q4 * 8) * 2);
#pragma unroll
    for (int mm = 0; mm < 4; ++mm) {
      int mt = w * 4 + mm;
      h16x8 af0 = *(const h16x8*)&aw1h[(mt * 16 + r) * 64 + q4 * 8];
      h16x8 af1 = *(const h16x8*)&aw1h[(mt * 16 + r) * 64 + 32 + q4 * 8];
      f32x4 acc[4];
#pragma unroll
      for (int nt = 0; nt < 4; ++nt) acc[nt] = (f32x4){0.f, 0.f, 0.f, 0.f};
#pragma unroll
      for (int nt = 0; nt < 4; ++nt)
        acc[nt] = __builtin_amdgcn_mfma_f32_16x16x32_f16(af0, bs[0][nt], acc[nt], 0, 0, 0);
#pragma unroll
      for (int nt = 0; nt < 4; ++nt)
        acc[nt] = __builtin_amdgcn_mfma_f32_16x16x32_f16(af1, bs[1][nt], acc[nt], 0, 0, 0);
      int j0 = mt * 16 + q4 * 4;
      f32x4 b1 = *(const f32x4*)&ab1[j0];
      f32x4 iv = *(const f32x4*)&invA[j0];
      f32x4 sh = *(const f32x4*)&shiftA[j0];
#pragma unroll
      for (int nt = 0; nt < 4; ++nt) {
        int col = nt * 16 + r;
        float v0 = fmaxf((acc[nt][0] + b1[0]) * iv[0] + sh[0], 0.f);
        float v1 = fmaxf((acc[nt][1] + b1[1]) * iv[1] + sh[1], 0.f);
        float v2 = fmaxf((acc[nt][2] + b1[2]) * iv[2] + sh[2], 0.f);
        float v3 = fmaxf((acc[nt][3] + b1[3]) * iv[3] + sh[3], 0.f);
        h16x4 pk = {(_Float16)v0, (_Float16)v1, (_Float16)v2, (_Float16)v3};
        *(h16x4*)(smem + SM_AL + (col * 260 + j0) * 2) = pk;
      }
    }
  }
  __syncthreads();

  // Phase D: GEMM2 logits = awt^T @ a (+abt); 2 half-rounds of write+softmax
  {
    f32x4 acc[2][4];
#pragma unroll
    for (int h = 0; h < 2; ++h)
#pragma unroll
      for (int nt = 0; nt < 4; ++nt) acc[h][nt] = (f32x4){0.f, 0.f, 0.f, 0.f};
    for (int ks = 0; ks < 8; ++ks) {
      h16x8 bsv[4];
#pragma unroll
      for (int nt = 0; nt < 4; ++nt)
        bsv[nt] = *(h16x8*)(smem + SM_AL + ((nt * 16 + r) * 260 + ks * 32 + q4 * 8) * 2);
#pragma unroll
      for (int h = 0; h < 2; ++h) {
        int mt2 = w * 2 + h;
        h16x8 af = *(const h16x8*)&awtP[(mt2 * 16 + r) * 256 + ks * 32 + q4 * 8];
#pragma unroll
        for (int nt = 0; nt < 4; ++nt)
          acc[h][nt] = __builtin_amdgcn_mfma_f32_16x16x32_f16(af, bsv[nt], acc[h][nt], 0, 0, 0);
      }
    }

    const int li0 = w * 16 + q4 * 4;
#pragma unroll
    for (int h = 0; h < 2; ++h) {
      if (h) __syncthreads();   // E(h=0) done reading lgc
      int orr0 = (w * 2 + h) * 16 + q4 * 4;
      f32x4 ab = *(const f32x4*)&abtX[orr0];
#pragma unroll
      for (int nt = 0; nt < 4; ++nt) {
        int col = nt * 16 + r;
        if (col < QPB * KNN) {
          f32x4 vv = acc[h][nt] + ab;
          h16x4 pk = {(_Float16)vv[0], (_Float16)vv[1], (_Float16)vv[2], (_Float16)vv[3]};
          *(h16x4*)(smem + SM_LGC + (col * 68 + li0) * 2) = pk;
        }
      }
      __syncthreads();
      // Phase E(h): softmax over k=20 + aggregation; 192 (li,p) pairs
      if (t < 64 * QPB) {
        int li = t & 63, p = t >> 6;
        if (n0 + p < NPTS) {
          int w2 = li >> 4;
          int orr = w2 * 32 + h * 16 + (li & 15);
          int o = orr >> 1, rb = orr & 1;
          float L[KNN];
#pragma unroll
          for (int kk = 0; kk < KNN; ++kk)
            L[kk] = (float)*(_Float16*)(smem + SM_LGC + (((p * 20 + kk) * 68 + li) * 2));
          float mx = L[0];
#pragma unroll
          for (int kk = 1; kk < KNN; ++kk) mx = fmaxf(mx, L[kk]);
          float s = 0.f;
#pragma unroll
          for (int kk = 0; kk < KNN; ++kk) { L[kk] = __expf(L[kk] - mx); s += L[kk]; }
          float rs = 1.0f / s;
          float a = 0.f;
#pragma unroll
          for (int kk = 0; kk < KNN; ++kk) {
            _Float16 gv = *(_Float16*)(smem + SM_VGB + (((p * 20 + kk) * 72 + o) * 2));
            a += L[kk] * (float)gv;
          }
          agg[(((size_t)(b * NPTS + n0 + p)) * UPF + rb) * DIM + o] = a * rs;
        }
      }
    }
  }
}

// ---------------------------------------------------------------------------
// out_proj (unchanged)
// ---------------------------------------------------------------------------
__global__ __launch_bounds__(256) void out_proj(const float* __restrict__ agg,
    const float* __restrict__ we, const float* __restrict__ be,
    const float* __restrict__ query, float* __restrict__ out) {
  __shared__ float A[64][65];
  const int b  = blockIdx.x >> 7;
  const int m0 = (blockIdx.x & 127) * 64;
  const int t  = threadIdx.x;
  for (int l = t; l < 64 * 64; l += 256) {
    int row = l >> 6, c = l & 63;
    A[row][c] = agg[(b * MOUT + m0 + row) * DIM + c];
  }
  __syncthreads();
  const int m_l = t & 63;
  const int w   = __builtin_amdgcn_readfirstlane(t >> 6);
  float acc[32];
#pragma unroll
  for (int i = 0; i < 32; ++i) acc[i] = 0.f;
  for (int c = 0; c < DIM; ++c) {
    float a = A[m_l][c];
#pragma unroll
    for (int i = 0; i < 32; ++i) acc[i] += we[(w * 32 + i) * DIM + c] * a;
  }
  const int m = m0 + m_l;
#pragma unroll
  for (int i = 0; i < 32; ++i) {
    int o = w * 32 + i;
    out[(b * CIN + o) * MOUT + m] = acc[i] + be[o] + query[(b * CIN + o) * NPTS + (m >> 1)];
  }
}

// ---------------------------------------------------------------------------
extern "C" void kernel_launch(void* const* d_in, const int* in_sizes, int n_in,
                              void* d_out, int out_size, void* d_ws, size_t ws_size,
                              hipStream_t stream) {
  (void)in_sizes; (void)n_in; (void)out_size; (void)ws_size;
  const float* pos1     = (const float*)d_in[0];
  const float* query    = (const float*)d_in[1];
  const float* pos2     = (const float*)d_in[2];
  const float* key_feat = (const float*)d_in[3];
  const float* wq  = (const float*)d_in[4];
  const float* bq  = (const float*)d_in[5];
  const float* wk  = (const float*)d_in[6];
  const float* bk  = (const float*)d_in[7];
  const float* wv  = (const float*)d_in[8];
  const float* bv  = (const float*)d_in[9];
  const float* pw1 = (const float*)d_in[10];
  const float* pb1 = (const float*)d_in[11];
  const float* pg  = (const float*)d_in[12];
  const float* pbt = (const float*)d_in[13];
  const float* pm  = (const float*)d_in[14];
  const float* pv  = (const float*)d_in[15];
  const float* pw2 = (const float*)d_in[16];
  const float* pb2 = (const float*)d_in[17];
  const float* aw1 = (const float*)d_in[18];
  const float* ab1 = (const float*)d_in[19];
  const float* ag  = (const float*)d_in[20];
  const float* abt2= (const float*)d_in[21];
  const float* am  = (const float*)d_in[22];
  const float* av  = (const float*)d_in[23];
  const float* awt = (const float*)d_in[24];
  const float* abt = (const float*)d_in[25];
  const float* we  = (const float*)d_in[26];
  const float* be  = (const float*)d_in[27];

  float* ws   = (float*)d_ws;
  float* q_t  = ws;
  float* k_t  = q_t + BATCH * NPTS * DIM;
  float* v_t  = k_t + BATCH * NPTS2 * DIM;
  float* aggb = v_t + BATCH * NPTS2 * DIM;
  int*   idxb = (int*)(aggb + BATCH * MOUT * DIM);
  _Float16* aw1h = (_Float16*)(idxb + BATCH * NPTS * KNN);
  _Float16* awtP = aw1h + HATT * DIM;
  _Float16* pw2h = awtP + 128 * HATT;
  float* invA    = (float*)(pw2h + DIM * HPOS);
  float* shiftA  = invA + HATT;
  float* abtX    = shiftA + HATT;
  float* pinvA   = abtX + 128;
  float* pshiftA = pinvA + HPOS;

  pack_weights<<<128, 256, 0, stream>>>(aw1, awt, pw2, ag, av, abt2, am, abt,
      pg, pv, pbt, pm, aw1h, awtP, pw2h, invA, shiftA, abtX, pinvA, pshiftA);
  proj_q <<<BATCH * (NPTS / 64), 256, 0, stream>>>(query, wq, bq, q_t);
  proj_kv<<<BATCH * (NPTS2 / 64), 256, 0, stream>>>(key_feat, wk, bk, wv, bv, k_t, v_t);
  knn_kernel<<<BATCH * NPTS / 4, 256, 0, stream>>>(pos1, pos2, idxb);
  attn_mfma<<<BATCH * BPB, 256, 0, stream>>>(q_t, k_t, v_t, idxb, pos1, pos2,
      pw1, pb1, pinvA, pshiftA, pw2h, pb2, aw1h, ab1, invA, shiftA, awtP, abtX, aggb);
  out_proj<<<BATCH * (MOUT / 64), 256, 0, stream>>>(aggb, we, be, query, (float*)d_out);
}